// Round 1
// baseline (209.447 us; speedup 1.0000x reference)
//
#include <hip/hip_runtime.h>

// Fused grouped-QKV GEMM: out[t,kv,g,d] = sum_e in[t,e]*W[e,kv,g,d] + bias[kv,g,d]
// then scattered to q (g<4), k (g==4), v (g==5) flat regions.
// M=64 tokens, K=4096, N=6144 (= 8 kv * 6 g * 128 d). fp32 in/out.
// Memory-bound: 100.7 MB weight read dominates -> target ~16.4us @6.3TB/s.
// bf16 MFMA (16x16x32) makes compute free (1.3us vs 20.5us fp32 VALU).

#define T_TOK   64
#define N_COLS  6144
#define K_DIM   4096
#define BN      16
#define BK      32
#define PITCH   40            // BK + 8 ushorts = 80B rows: 16B-aligned, ~2-way banks
#define NKT     (K_DIM / BK)  // 128
#define Q_SZ    (64 * 4096)   // 262144
#define K_OFF   Q_SZ
#define V_OFF   (Q_SZ + 64 * 1024)

typedef __bf16 bf16x8 __attribute__((ext_vector_type(8)));
typedef float  f32x4  __attribute__((ext_vector_type(4)));
typedef unsigned short us8 __attribute__((ext_vector_type(8)));
typedef unsigned short us2 __attribute__((ext_vector_type(2)));

__device__ __forceinline__ unsigned short f2bf(float f) {
    // round-to-nearest-even f32 -> bf16 (inputs are finite normals)
    unsigned int u = __float_as_uint(f);
    u += 0x7FFFu + ((u >> 16) & 1u);
    return (unsigned short)(u >> 16);
}

__global__ __launch_bounds__(256, 4)
void qkv_fused_kernel(const float* __restrict__ in,
                      const float* __restrict__ w,
                      const float* __restrict__ bias,
                      float* __restrict__ out) {
    // LDS tiles, stored as bf16 bit-patterns. Bs is TRANSPOSED: [n][k].
    __shared__ __align__(16) unsigned short As[T_TOK][PITCH];
    __shared__ __align__(16) unsigned short Bs[BN][PITCH];

    const int tid = threadIdx.x;
    const int n0  = blockIdx.x * BN;

    // A-staging role: thread -> (token, k-quad of 8)
    const int atok = tid >> 2;        // 0..63
    const int akq  = (tid & 3) * 8;   // 0,8,16,24
    // B-staging role: thread -> (col n, k-pair)
    const int bn = tid & 15;          // 0..15
    const int bk = (tid >> 4) * 2;    // 0,2,..,30

    const int wid  = tid >> 6;        // wave id: token chunk 16*wid
    const int lane = tid & 63;
    const int l15  = lane & 15;
    const int kblk = lane >> 4;       // 0..3

    f32x4 acc = {0.f, 0.f, 0.f, 0.f};

    // prefetch k-tile 0 into registers
    const float* ap = in + atok * K_DIM + akq;
    const float* bp = w + bk * N_COLS + n0 + bn;
    float4 a0 = *(const float4*)(ap);
    float4 a1 = *(const float4*)(ap + 4);
    float  b0 = bp[0];
    float  b1 = bp[N_COLS];

    for (int kt = 0; kt < NKT; ++kt) {
        __syncthreads();  // WAR: previous iteration's ds_reads complete

        // stage current tile (fp32 regs -> bf16 -> LDS)
        us8 av;
        av[0] = f2bf(a0.x); av[1] = f2bf(a0.y); av[2] = f2bf(a0.z); av[3] = f2bf(a0.w);
        av[4] = f2bf(a1.x); av[5] = f2bf(a1.y); av[6] = f2bf(a1.z); av[7] = f2bf(a1.w);
        *(us8*)&As[atok][akq] = av;                       // ds_write_b128
        us2 bv2; bv2[0] = f2bf(b0); bv2[1] = f2bf(b1);
        *(us2*)&Bs[bn][bk] = bv2;                         // ds_write_b32 (transposed)

        // issue next tile's global loads (a full iteration to cover latency)
        if (kt + 1 < NKT) {
            const float* apn = in + atok * K_DIM + (kt + 1) * BK + akq;
            a0 = *(const float4*)(apn);
            a1 = *(const float4*)(apn + 4);
            const float* bpn = w + ((kt + 1) * BK + bk) * N_COLS + n0 + bn;
            b0 = bpn[0];
            b1 = bpn[N_COLS];
        }

        __syncthreads();  // RAW: tile staged

        // fragments: A[m=l15][k=kblk*8+j], B[k=kblk*8+j][n=l15] (Bs transposed)
        us8 au = *(const us8*)&As[16 * wid + l15][kblk * 8];   // ds_read_b128
        us8 bu = *(const us8*)&Bs[l15][kblk * 8];              // ds_read_b128
        acc = __builtin_amdgcn_mfma_f32_16x16x32_bf16(
            __builtin_bit_cast(bf16x8, au), __builtin_bit_cast(bf16x8, bu),
            acc, 0, 0, 0);
    }

    // epilogue: C/D layout col=lane&15 (n), row=kblk*4+reg (token within chunk)
    const int kv = n0 / 768;            // block-uniform
    const int g  = (n0 / 128) % 6;      // block-uniform (BN=16 divides 128)
    const int d  = (n0 % 128) + l15;
    const float bvv = bias[n0 + l15];

    const int t0 = 16 * wid + kblk * 4;
    #pragma unroll
    for (int r = 0; r < 4; ++r) {
        const int t = t0 + r;
        const float val = acc[r] + bvv;
        int idx;
        if (g < 4)       idx = t * 4096 + kv * 512 + g * 128 + d;  // q
        else if (g == 4) idx = K_OFF + t * 1024 + kv * 128 + d;    // k
        else             idx = V_OFF + t * 1024 + kv * 128 + d;    // v
        out[idx] = val;
    }
}

extern "C" void kernel_launch(void* const* d_in, const int* in_sizes, int n_in,
                              void* d_out, int out_size, void* d_ws, size_t ws_size,
                              hipStream_t stream) {
    const float* in   = (const float*)d_in[0];  // [64, 4096]
    const float* w    = (const float*)d_in[1];  // [4096, 8, 6, 128]
    const float* bias = (const float*)d_in[2];  // [8, 6, 128]
    float* out = (float*)d_out;                 // q|k|v concat = 393216 floats

    qkv_fused_kernel<<<N_COLS / BN, 256, 0, stream>>>(in, w, bias, out);
}

// Round 2
// 187.840 us; speedup vs baseline: 1.1150x; 1.1150x over previous
//
#include <hip/hip_runtime.h>

// Fused grouped-QKV GEMM: out[t,kv,g,d] = sum_e in[t,e]*W[e,kv,g,d] + bias
// M=64, K=4096, N=6144. fp32 in/out. Weight read (100.7MB) dominates ->
// memory-bound floor ~16.5us @6.3TB/s.
//
// R1 lesson: LDS+2-barrier K-loop at 384 blocks serialized on HBM latency
// (13% BW). R2: barrier-free K-loop, B-frags loaded straight from global
// (perfect 64B-line coalescing: for each j, 64 lanes cover W[k][n0..n15]
// over 4 k-rows), A-frags from a pre-converted bf16 copy of the input.
// Split-K x8 (2 blocks/n-tile x 4 waves/block), LDS reduce across the 4
// waves of a block, 2-way fp32 atomicAdd into bias-initialized out.

#define N_COLS 6144
#define K_DIM  4096
#define Q_SZ   (64 * 4096)
#define K_OFF  Q_SZ
#define V_OFF  (Q_SZ + 64 * 1024)
#define OUT_ELEMS 393216   // 64*6144
#define IN_ELEMS  262144   // 64*4096

typedef __bf16 bf16x8 __attribute__((ext_vector_type(8)));
typedef float  f32x4  __attribute__((ext_vector_type(4)));
typedef unsigned short us8 __attribute__((ext_vector_type(8)));

// bf16 copy of the input, rewritten by init_kernel on every call
__device__ unsigned short g_abuf[IN_ELEMS];

__device__ __forceinline__ unsigned short f2bf_rne(float f) {
    unsigned int u = __float_as_uint(f);
    u += 0x7FFFu + ((u >> 16) & 1u);
    return (unsigned short)(u >> 16);
}

__device__ __forceinline__ int out_index(int t, int n) {
    const int kv = n / 768;
    const int g  = (n >> 7) % 6;
    const int d  = n & 127;
    if (g < 4)  return t * 4096 + kv * 512 + g * 128 + d;   // q
    if (g == 4) return K_OFF + t * 1024 + kv * 128 + d;     // k
    return V_OFF + t * 1024 + kv * 128 + d;                 // v
}

// out <- bias broadcast (so gemm can atomicAdd); g_abuf <- bf16(in)
__global__ __launch_bounds__(256)
void init_kernel(const float* __restrict__ in, const float* __restrict__ bias,
                 float* __restrict__ out) {
    const int i = blockIdx.x * 256 + threadIdx.x;
    if (i < IN_ELEMS) g_abuf[i] = f2bf_rne(in[i]);
    if (i < OUT_ELEMS) {
        // i = ((t*8 + kv)*6 + g)*128 + d
        const int d   = i & 127;
        const int g   = (i >> 7) % 6;
        const int kvt = i / 768;
        const int kv  = kvt & 7;
        const int t   = kvt >> 3;
        out[out_index(t, kv * 768 + g * 128 + d)] = bias[(kv * 6 + g) * 128 + d];
    }
}

__global__ __launch_bounds__(256, 3)
void qkv_gemm(const float* __restrict__ w, float* __restrict__ out) {
    __shared__ float red[4][64][17];  // +1 pad: conflict-free reduce

    const int tid  = threadIdx.x;
    const int nt   = blockIdx.x >> 1;   // n-tile 0..383
    const int kh   = blockIdx.x & 1;    // k half
    const int n0   = nt * 16;
    const int wid  = tid >> 6;
    const int lane = tid & 63;
    const int l15  = lane & 15;
    const int kblk = lane >> 4;
    const int ks   = kh * 2048 + wid * 512;  // this wave's 512-wide k split

    f32x4 acc[4] = {{0.f,0.f,0.f,0.f},{0.f,0.f,0.f,0.f},
                    {0.f,0.f,0.f,0.f},{0.f,0.f,0.f,0.f}};

    const float* bbase = w + (size_t)(ks + kblk * 8) * N_COLS + n0 + l15;
    const unsigned short* abase = g_abuf + l15 * K_DIM + ks + kblk * 8;

    #pragma unroll 4
    for (int kk = 0; kk < 512; kk += 32) {
        // B-frag: B[k=kblk*8+j][n=l15] straight from global, 8 dwords/lane.
        const float* bp = bbase + (size_t)kk * N_COLS;
        unsigned int b[8];
        #pragma unroll
        for (int j = 0; j < 8; ++j)
            b[j] = __float_as_uint(bp[(size_t)j * N_COLS]);

        // A-frags (bf16, k-contiguous): tokens tc*16 + l15
        us8 au0 = *(const us8*)(abase + kk);
        us8 au1 = *(const us8*)(abase + 16 * K_DIM + kk);
        us8 au2 = *(const us8*)(abase + 32 * K_DIM + kk);
        us8 au3 = *(const us8*)(abase + 48 * K_DIM + kk);

        // fp32 -> bf16 (round half up) + pack pairs
        union { unsigned int u[4]; us8 v; } pk;
        #pragma unroll
        for (int j = 0; j < 4; ++j) {
            const unsigned int lo = b[2 * j]     + 0x8000u;
            const unsigned int hi = b[2 * j + 1] + 0x8000u;
            pk.u[j] = (hi & 0xFFFF0000u) | (lo >> 16);
        }
        const bf16x8 bf = __builtin_bit_cast(bf16x8, pk.v);

        acc[0] = __builtin_amdgcn_mfma_f32_16x16x32_bf16(
                     __builtin_bit_cast(bf16x8, au0), bf, acc[0], 0, 0, 0);
        acc[1] = __builtin_amdgcn_mfma_f32_16x16x32_bf16(
                     __builtin_bit_cast(bf16x8, au1), bf, acc[1], 0, 0, 0);
        acc[2] = __builtin_amdgcn_mfma_f32_16x16x32_bf16(
                     __builtin_bit_cast(bf16x8, au2), bf, acc[2], 0, 0, 0);
        acc[3] = __builtin_amdgcn_mfma_f32_16x16x32_bf16(
                     __builtin_bit_cast(bf16x8, au3), bf, acc[3], 0, 0, 0);
    }

    // reduce the 4 waves' partials (4 k-splits of this block) in LDS
    #pragma unroll
    for (int tc = 0; tc < 4; ++tc)
        #pragma unroll
        for (int r = 0; r < 4; ++r)
            red[wid][lane][tc * 4 + r] = acc[tc][r];
    __syncthreads();

    const int l  = tid & 63;
    const int i0 = (tid >> 6) * 4;
    const int rl15  = l & 15;
    const int rkblk = l >> 4;
    #pragma unroll
    for (int r2 = 0; r2 < 4; ++r2) {
        const int i = i0 + r2;
        const float s = red[0][l][i] + red[1][l][i] + red[2][l][i] + red[3][l][i];
        const int tc = i >> 2, r = i & 3;
        const int t = tc * 16 + rkblk * 4 + r;          // C/D: row = quad*4+reg
        atomicAdd(&out[out_index(t, n0 + rl15)], s);    // 2 contributions/elem
    }
}

extern "C" void kernel_launch(void* const* d_in, const int* in_sizes, int n_in,
                              void* d_out, int out_size, void* d_ws, size_t ws_size,
                              hipStream_t stream) {
    const float* in   = (const float*)d_in[0];  // [64, 4096]
    const float* w    = (const float*)d_in[1];  // [4096, 8, 6, 128]
    const float* bias = (const float*)d_in[2];  // [8, 6, 128]
    float* out = (float*)d_out;

    init_kernel<<<(OUT_ELEMS + 255) / 256, 256, 0, stream>>>(in, bias, out);
    qkv_gemm<<<768, 256, 0, stream>>>(w, out);
}